// Round 1
// 408.439 us; speedup vs baseline: 1.0200x; 1.0200x over previous
//
#include <hip/hip_runtime.h>
#include <hip/hip_bf16.h>
#include <cstdint>
#include <cstddef>

// ArcFace FC: out[i][j] = S * (j==label[i] ? phi(cos_ij) : cos_ij)
// cos = normalize(x) @ normalize(W)^T,  B=512, D=512, C=100000
//
// v2: W-normalization fused into the GEMM. W is read ONCE as fp32, converted
// to bf16 in-register during LDS staging; per-row 1/||w|| is accumulated from
// the staged fp32 values and applied in the epilogue (exact scaling after the
// dot product). Eliminates the 205 MB re-read + 102 MB bf16 round-trip of the
// old norm pass. x (1 MB) keeps a tiny pre-normalize pass.

#define SSCALE 30.0f
#define COSM_  0.8775825618903728f
#define SINM_  0.4794255386042030f
#define TH_    (-0.8775825618903728f)
#define MM_    0.2397127693021015f
#define EPS_   1e-12f

typedef unsigned short ushort_t;
typedef __attribute__((ext_vector_type(8))) short bf16x8;
typedef __attribute__((ext_vector_type(16))) float f32x16;

__device__ inline ushort_t f2bf(float f) {
    union { float f; unsigned u; } x; x.f = f;
    unsigned r = (x.u + 0x7fffu + ((x.u >> 16) & 1u)) >> 16;
    return (ushort_t)r;
}

// HW RNE f32->bf16 (compiler emits v_cvt_pk_bf16_f32; m240: scalar cast beats
// hand-written inline asm)
__device__ inline ushort_t bfbits(float f) {
    union { __hip_bfloat16 h; ushort_t u; } c;
    c.h = __float2bfloat16(f);
    return c.u;
}

__device__ inline bf16x8 cvt8(float4 a, float4 b) {
    bf16x8 r;
    r[0] = (short)bfbits(a.x); r[1] = (short)bfbits(a.y);
    r[2] = (short)bfbits(a.z); r[3] = (short)bfbits(a.w);
    r[4] = (short)bfbits(b.x); r[5] = (short)bfbits(b.y);
    r[6] = (short)bfbits(b.z); r[7] = (short)bfbits(b.w);
    return r;
}

// ---------------- normalize x rows (D=512) fp32 -> bf16 (tiny: 512 rows) ----
__global__ __launch_bounds__(256) void norm_rows_bf16(const float* __restrict__ src,
                                                      ushort_t* __restrict__ dst,
                                                      int nrows) {
    int row = blockIdx.x * 4 + (threadIdx.x >> 6);
    if (row >= nrows) return;
    int lane = threadIdx.x & 63;
    const float* s = src + (size_t)row * 512;
    float4 a = ((const float4*)s)[lane];
    float4 b = ((const float4*)s)[lane + 64];
    float ss = a.x*a.x + a.y*a.y + a.z*a.z + a.w*a.w
             + b.x*b.x + b.y*b.y + b.z*b.z + b.w*b.w;
    #pragma unroll
    for (int off = 32; off > 0; off >>= 1) ss += __shfl_down(ss, off, 64);
    ss = __shfl(ss, 0, 64);
    float inv = 1.0f / fmaxf(sqrtf(ss), EPS_);
    ushort_t* d = dst + (size_t)row * 512;
    union { ushort_t u[4]; uint2 v; } oa, ob;
    oa.u[0] = f2bf(a.x * inv); oa.u[1] = f2bf(a.y * inv);
    oa.u[2] = f2bf(a.z * inv); oa.u[3] = f2bf(a.w * inv);
    ob.u[0] = f2bf(b.x * inv); ob.u[1] = f2bf(b.y * inv);
    ob.u[2] = f2bf(b.z * inv); ob.u[3] = f2bf(b.w * inv);
    ((uint2*)d)[lane]      = oa.v;
    ((uint2*)d)[lane + 64] = ob.v;
}

// ---------------- fused bf16 MFMA GEMM with in-kernel W norm ----------------
// out[M,N] = S * A[M,K] @ (W[N,K] * invw[N])^T,  A already normalized bf16.
// 128x128 tile, BK=32, 4 waves each 64x64 via 2x2 of 32x32x16 MFMA.
// LDS layout (per operand): 128 rows x 4 chunks of 16B, chunk XOR-swizzled by
// (row>>1)&3 so 32x32 fragment ds_read_b128 hits all 32 banks.
// A staged with global_load_lds (linear dest realizes swizzle via source pick).
// W staged fp32 global->reg, cvt->bf16, ds_write_b128 to the SAME slot layout;
// sum-of-squares accumulated from the fp32 values while staging.
__global__ __launch_bounds__(256) void gemm_fused(const ushort_t* __restrict__ A,
                                                  const float* __restrict__ W,
                                                  float* __restrict__ out,
                                                  int M, int N, int K) {
    __shared__ ushort_t lA[128 * 32];
    __shared__ ushort_t lB[128 * 32];
    __shared__ float sInv[128];
    int tid  = threadIdx.x;
    int wave = tid >> 6, lane = tid & 63;
    int half = lane >> 5, n5 = lane & 31;
    int bm = blockIdx.x, bn = blockIdx.y;

    f32x16 acc[2][2];
    #pragma unroll
    for (int mt = 0; mt < 2; mt++)
        #pragma unroll
        for (int nt = 0; nt < 2; nt++)
            #pragma unroll
            for (int r = 0; r < 16; r++)
                acc[mt][nt][r] = 0.f;

    // staging geometry: thread t owns 16B slot t (rows 0-63) and slot 256+t
    // (rows 64-127).  slot = row*4 + (chunk ^ ((row>>1)&3));
    // row = t>>2 (+64), stored chunk c0 = (t&3) ^ ((t>>3)&3) for both.
    int srow = tid >> 2;
    int c0   = (tid & 3) ^ ((tid >> 3) & 3);
    int arow = bm * 128 + srow;
    int br0 = bn * 128 + srow;        if (br0 > N - 1) br0 = N - 1;
    int br1 = bn * 128 + 64 + srow;   if (br1 > N - 1) br1 = N - 1;
    const ushort_t* ag0 = A + (size_t)arow * K + c0 * 8;
    const ushort_t* ag1 = ag0 + (size_t)64 * K;
    const float* wg0 = W + (size_t)br0 * K + c0 * 8;
    const float* wg1 = W + (size_t)br1 * K + c0 * 8;

    // wave-uniform LDS bases for A (HW adds lane*16 bytes)
    ushort_t* lA0 = lA + wave * 512;
    ushort_t* lA1 = lA + 2048 + wave * 512;
    // per-thread 16B W slots (same linear addresses global_load_lds would hit)
    bf16x8* lBs0 = (bf16x8*)lB + tid;
    bf16x8* lBs1 = (bf16x8*)lB + 256 + tid;

    // fragment read bases: row r, k = ks*16 + half*8 + j
    // ushort idx = r*32 + (c ^ ((r>>1)&3))*8,  c = ks*2 + half
    int sw  = (n5 >> 1) & 3;             // row bases are mult of 32
    int cs0 = (half ^ sw) * 8;           // ks=0
    int cs1 = ((2 ^ half ^ sw)) * 8;     // ks=1
    const ushort_t* pArow = lA + ((wave >> 1) * 64 + n5) * 32;
    const ushort_t* pBrow = lB + ((wave & 1) * 64 + n5) * 32;

    float ss0 = 0.f, ss1 = 0.f;

    for (int k0 = 0; k0 < K; k0 += 32) {
        // issue W fp32 loads BEFORE the barrier: latency overlaps barrier wait
        float4 u0 = *(const float4*)(wg0 + k0);
        float4 u1 = *(const float4*)(wg0 + k0 + 4);
        float4 v0 = *(const float4*)(wg1 + k0);
        float4 v1 = *(const float4*)(wg1 + k0 + 4);
        if (k0) __syncthreads();
        __builtin_amdgcn_global_load_lds((const __attribute__((address_space(1))) void*)(ag0 + k0),
                                         (__attribute__((address_space(3))) void*)lA0, 16, 0, 0);
        __builtin_amdgcn_global_load_lds((const __attribute__((address_space(1))) void*)(ag1 + k0),
                                         (__attribute__((address_space(3))) void*)lA1, 16, 0, 0);
        ss0 += u0.x*u0.x + u0.y*u0.y + u0.z*u0.z + u0.w*u0.w
             + u1.x*u1.x + u1.y*u1.y + u1.z*u1.z + u1.w*u1.w;
        ss1 += v0.x*v0.x + v0.y*v0.y + v0.z*v0.z + v0.w*v0.w
             + v1.x*v1.x + v1.y*v1.y + v1.z*v1.z + v1.w*v1.w;
        *lBs0 = cvt8(u0, u1);
        *lBs1 = cvt8(v0, v1);
        __syncthreads();

        bf16x8 af[2][2], bfr[2][2];
        #pragma unroll
        for (int mt = 0; mt < 2; mt++) {
            af[mt][0] = *(const bf16x8*)(pArow + mt * 1024 + cs0);
            af[mt][1] = *(const bf16x8*)(pArow + mt * 1024 + cs1);
        }
        #pragma unroll
        for (int nt = 0; nt < 2; nt++) {
            bfr[nt][0] = *(const bf16x8*)(pBrow + nt * 1024 + cs0);
            bfr[nt][1] = *(const bf16x8*)(pBrow + nt * 1024 + cs1);
        }
        #pragma unroll
        for (int ks = 0; ks < 2; ks++)
            #pragma unroll
            for (int mt = 0; mt < 2; mt++)
                #pragma unroll
                for (int nt = 0; nt < 2; nt++)
                    acc[mt][nt] = __builtin_amdgcn_mfma_f32_32x32x16_bf16(
                        af[mt][ks], bfr[nt][ks], acc[mt][nt], 0, 0, 0);
    }

    // reduce sum-of-squares across the 4 threads sharing a row (consecutive
    // 4-aligned lanes), then publish 1/||w|| for this tile's 128 rows.
    ss0 += __shfl_xor(ss0, 1, 64); ss0 += __shfl_xor(ss0, 2, 64);
    ss1 += __shfl_xor(ss1, 1, 64); ss1 += __shfl_xor(ss1, 2, 64);
    if ((tid & 3) == 0) {
        sInv[srow]      = 1.0f / fmaxf(sqrtf(ss0), EPS_);
        sInv[srow + 64] = 1.0f / fmaxf(sqrtf(ss1), EPS_);
    }
    __syncthreads();

    // epilogue: 32x32 C/D layout col = lane&31, row = (reg&3) + 8*(reg>>2) + 4*half
    int row0 = bm * 128 + (wave >> 1) * 64 + 4 * half;
    int clbase = (wave & 1) * 64 + n5;
    #pragma unroll
    for (int nt = 0; nt < 2; nt++) {
        int cl = clbase + nt * 32;
        int c  = bn * 128 + cl;
        if (c < N) {
            float sc = sInv[cl] * SSCALE;
            #pragma unroll
            for (int mt = 0; mt < 2; mt++) {
                #pragma unroll
                for (int r = 0; r < 16; r++) {
                    int row = row0 + mt * 32 + (r & 3) + 8 * (r >> 2);
                    __builtin_nontemporal_store(acc[mt][nt][r] * sc,
                                                &out[(size_t)row * N + c]);
                }
            }
        }
    }
}

// ---------------- fixup: apply arcface margin at (i, label[i]) ---------------
__global__ void fixup_kernel(const int* __restrict__ label, float* __restrict__ out,
                             int Bsz, int C) {
    int i = blockIdx.x * blockDim.x + threadIdx.x;
    if (i >= Bsz) return;
    int j = label[i];
    size_t idx = (size_t)i * C + j;
    float cosv = out[idx] * (1.0f / SSCALE);
    float sinv = sqrtf(fmaxf(0.f, 1.f - cosv * cosv));
    float phi = cosv * COSM_ - sinv * SINM_;
    if (!(cosv > TH_)) phi = cosv - MM_;
    out[idx] = phi * SSCALE;
}

// ---------------- fallback path (workspace too small / odd shapes) ----------
__global__ __launch_bounds__(256) void rownorm_inv(const float* __restrict__ in,
                                                   float* __restrict__ invn, int nrows) {
    int row = blockIdx.x * 4 + (threadIdx.x >> 6);
    if (row >= nrows) return;
    int lane = threadIdx.x & 63;
    const float4* p = (const float4*)(in + (size_t)row * 512);
    float4 a = p[lane];
    float4 b = p[lane + 64];
    float ss = a.x*a.x + a.y*a.y + a.z*a.z + a.w*a.w
             + b.x*b.x + b.y*b.y + b.z*b.z + b.w*b.w;
    #pragma unroll
    for (int off = 32; off > 0; off >>= 1) ss += __shfl_down(ss, off, 64);
    if (lane == 0) invn[row] = 1.0f / fmaxf(sqrtf(ss), EPS_);
}

__global__ __launch_bounds__(256) void naive_gemm(const float* __restrict__ x,
                                                  const float* __restrict__ w,
                                                  const float* __restrict__ invx,
                                                  const float* __restrict__ invw,
                                                  float* __restrict__ out, int Bsz, int C) {
    __shared__ float xs[512];
    int i = blockIdx.y;
    int j = blockIdx.x * 256 + threadIdx.x;
    for (int k = threadIdx.x; k < 512; k += 256) xs[k] = x[(size_t)i * 512 + k];
    __syncthreads();
    if (j >= C) return;
    const float* wr = w + (size_t)j * 512;
    float acc = 0.f;
    for (int k = 0; k < 512; k++) acc += xs[k] * wr[k];
    out[(size_t)i * C + j] = acc * invx[i] * invw[j] * SSCALE;
}

extern "C" void kernel_launch(void* const* d_in, const int* in_sizes, int n_in,
                              void* d_out, int out_size, void* d_ws, size_t ws_size,
                              hipStream_t stream) {
    const float* x = (const float*)d_in[0];
    const float* w = (const float*)d_in[1];
    const int* label = (const int*)d_in[2];
    float* out = (float*)d_out;

    const int Bsz = in_sizes[2];            // 512
    const int D   = 512;
    const int C   = in_sizes[1] / D;        // 100000

    size_t need = (size_t)Bsz * D * sizeof(ushort_t);   // xn only: 512 KB
    if (ws_size >= need && (Bsz % 128) == 0) {
        ushort_t* xn = (ushort_t*)d_ws;
        norm_rows_bf16<<<(Bsz + 3) / 4, 256, 0, stream>>>(x, xn, Bsz);
        dim3 grid(Bsz / 128, (C + 127) / 128);   // m fastest -> W-tile L2/L3 reuse
        gemm_fused<<<grid, 256, 0, stream>>>(xn, w, out, Bsz, C, D);
    } else {
        float* invx = (float*)d_ws;
        float* invw = invx + Bsz;
        rownorm_inv<<<(Bsz + 3) / 4, 256, 0, stream>>>(x, invx, Bsz);
        rownorm_inv<<<(C + 3) / 4, 256, 0, stream>>>(w, invw, C);
        dim3 g((C + 255) / 256, Bsz);
        naive_gemm<<<g, 256, 0, stream>>>(x, w, invx, invw, out, Bsz, C);
    }
    fixup_kernel<<<(Bsz + 255) / 256, 256, 0, stream>>>(label, out, Bsz, C);
}